// Round 16
// baseline (1310.252 us; speedup 1.0000x reference)
//
#include <hip/hip_runtime.h>
#include <stdint.h>

// Problem constants (from reference)
#define NN      5000
#define NB      8
#define TSTEPS  256
#define NDELAY  15
#define NW      157          // uint32 words covering 5000 presyn bits
#define NIPAD   5120         // padded neuron dim (columns of maskT2)
#define RW      160          // ring row stride in words (640 B, 16B-aligned)
#define IPB     256          // threads per block
#define BPB     20           // blocks per batch
#define NBLK    (NB*BPB)     // 160 blocks -> 1 per CU, co-resident
#define CH      4            // chunk length (64 chunks)
#define NCHUNK  (TSTEPS/CH)  // 64
#define BARSTRIDE 16         // ints between chunk counters (64B apart)
#define RING_DEPTH 256       // WRITE-ONCE ring: slot = step + 15 (no reuse)

// Workspace layout (bytes)
#define MASK_BYTES (NW*NIPAD*4)              // 3,215,360
#define BAR_OFF    MASK_BYTES
#define BAR_BYTES  (64*BARSTRIDE*4)          // 4,096
#define RING_OFF   (BAR_OFF + BAR_BYTES)     // 16B-aligned
#define RING_BYTES (RING_DEPTH*NB*RW*4)      // 1,310,720
#define ZERO_BYTES (RING_OFF + RING_BYTES)   // ~4.53 MB total

// ---------------------------------------------------------------------------
// Kernel 1: bit-pack connectivity, word-major-transposed:
//   maskT2[w*NIPAD + i] bit (j&31), w=j>>5, set iff W[i,j] != 0.
// ---------------------------------------------------------------------------
__global__ void _Brunel_build_mask(const float* __restrict__ W,
                                   uint32_t* __restrict__ maskT2)
{
    int j = blockIdx.x * blockDim.x + threadIdx.x;   // presyn 0..5119
    int i = blockIdx.y;                              // postsyn row 0..4999
    int lane = threadIdx.x & 63;
    bool nz = false;
    if (j < NN) nz = (W[(size_t)i * NN + j] != 0.0f);
    unsigned long long m = __ballot(nz);
    if ((lane & 31) == 0 && j < NN) {
        uint32_t wd = (lane == 0) ? (uint32_t)m : (uint32_t)(m >> 32);
        maskT2[(size_t)(j >> 5) * NIPAD + i] = wd;
    }
}

// ---------------------------------------------------------------------------
// Kernel 2: persistent SNN sim.
//  Round-16 = R13 (uniform cached loads from write-once ring, VALU-floor
//  popc consume, mask rows in LDS) + EXPLICIT software pipelining of the
//  spike loads: 10 blocks of 4 word-groups, ping-pong staged in 32 named
//  uint4 registers, next block's 16 loads issued before processing the
//  current block (load->use distance ~1 block ~384cyc, covers L2/LLC
//  latency that R13 left exposed at ~1-iteration distance). Word-156
//  dwords issued at chunk start, consumed at chunk end.
//  Sync: per-chunk barc, gate poll barc[m-3], sc0sc1 ring stores,
//  vmcnt(0)+barrier arrive -- R8..R13 proven.
// ---------------------------------------------------------------------------
__global__ void __launch_bounds__(IPB, 1) _Brunel_persist(
    const float* __restrict__ ext,
    const uint32_t* __restrict__ maskT2,
    uint32_t* __restrict__ ring,
    int* __restrict__ barc,
    float* __restrict__ out_spk,
    float* __restrict__ out_vs)
{
    const int tx   = threadIdx.x;
    const int bb   = blockIdx.x;
    const int b    = bb / BPB;
    const int i    = (bb % BPB) * IPB + tx;
    const bool act = (i < NN);
    const int lane = tx & 63;

    __shared__ __align__(16) uint32_t s_mask[IPB][156];   // 159,744 B
    __shared__ uint32_t s_mask156[IPB];                   //   1,024 B

    // ---- one-time: mask row -> LDS (own row only; coalesced over tx) ----
    for (int w = 0; w < NW; ++w) {
        uint32_t mv = maskT2[(size_t)w * NIPAD + i];      // pad cols are 0
        if (w < 156) s_mask[tx][w] = mv; else s_mask156[tx] = mv;
    }
    __syncthreads();

    float v = 0.0f;

    for (int t0 = 0, m = 0; t0 < TSTEPS; t0 += CH, ++m) {
        // ---- prefetch external inputs for this chunk ----
        float x0 = 0.f, x1 = 0.f, x2 = 0.f, x3 = 0.f;
        if (act) {
            const float* e0 = ext + ((size_t)t0 * NB + b) * NN + i;
            const size_t st = (size_t)NB * NN;
            x0 = e0[0]; x1 = e0[st]; x2 = e0[2 * st]; x3 = e0[3 * st];
        }

        // ---- gate: all blocks finished chunk m-3 (writers of our slots) ----
        if (m >= 3) {
            if (tx == 0) {
                const int* c3 = barc + (size_t)(m - 3) * BARSTRIDE;
                while (__hip_atomic_load(c3, __ATOMIC_RELAXED,
                                         __HIP_MEMORY_SCOPE_AGENT) < NBLK)
                    __builtin_amdgcn_s_sleep(2);
            }
            __syncthreads();     // no reads may pass the gate
        }

        // ---- spike rows: slots t0..t0+3 of the write-once ring ----
        const uint4* __restrict__ s0 =
            (const uint4*)(ring + ((size_t)(t0 + 0) * NB + b) * RW);
        const uint4* __restrict__ s1 =
            (const uint4*)(ring + ((size_t)(t0 + 1) * NB + b) * RW);
        const uint4* __restrict__ s2 =
            (const uint4*)(ring + ((size_t)(t0 + 2) * NB + b) * RW);
        const uint4* __restrict__ s3 =
            (const uint4*)(ring + ((size_t)(t0 + 3) * NB + b) * RW);

        int cE0 = 0, cE1 = 0, cE2 = 0, cE3 = 0;
        int cI0 = 0, cI1 = 0, cI2 = 0, cI3 = 0;
        const uint32_t* __restrict__ mrow = s_mask[tx];

        // ---- ping-pong staging registers: 32 uint4 (128 VGPRs) ----
        uint4 Aa0,Aa1,Aa2,Aa3, Ab0,Ab1,Ab2,Ab3,
              Ac0,Ac1,Ac2,Ac3, Ad0,Ad1,Ad2,Ad3;
        uint4 Ba0,Ba1,Ba2,Ba3, Bb0,Bb1,Bb2,Bb3,
              Bc0,Bc1,Bc2,Bc3, Bd0,Bd1,Bd2,Bd3;

#define LOAD4Q(P, CB)                                                         \
        P##a0 = s0[(CB)+0]; P##a1 = s1[(CB)+0];                               \
        P##a2 = s2[(CB)+0]; P##a3 = s3[(CB)+0];                               \
        P##b0 = s0[(CB)+1]; P##b1 = s1[(CB)+1];                               \
        P##b2 = s2[(CB)+1]; P##b3 = s3[(CB)+1];                               \
        P##c0 = s0[(CB)+2]; P##c1 = s1[(CB)+2];                               \
        P##c2 = s2[(CB)+2]; P##c3 = s3[(CB)+2];                               \
        P##d0 = s0[(CB)+3]; P##d1 = s1[(CB)+3];                               \
        P##d2 = s2[(CB)+3]; P##d3 = s3[(CB)+3];

#define LOAD3Q(P, CB)                                                         \
        P##a0 = s0[(CB)+0]; P##a1 = s1[(CB)+0];                               \
        P##a2 = s2[(CB)+0]; P##a3 = s3[(CB)+0];                               \
        P##b0 = s0[(CB)+1]; P##b1 = s1[(CB)+1];                               \
        P##b2 = s2[(CB)+1]; P##b3 = s3[(CB)+1];                               \
        P##c0 = s0[(CB)+2]; P##c1 = s1[(CB)+2];                               \
        P##c2 = s2[(CB)+2]; P##c3 = s3[(CB)+2];

#define ADDW(MW, WIDX, W0, W1, W2, W3)                                        \
        if ((WIDX) < 125) {                                                   \
            cE0 += __popc((MW)&(W0)); cE1 += __popc((MW)&(W1));               \
            cE2 += __popc((MW)&(W2)); cE3 += __popc((MW)&(W3));               \
        } else {                                                              \
            cI0 += __popc((MW)&(W0)); cI1 += __popc((MW)&(W1));               \
            cI2 += __popc((MW)&(W2)); cI3 += __popc((MW)&(W3));               \
        }

#define PROCC(CB, Q0, Q1, Q2, Q3)                                             \
        { uint4 m4_ = *(const uint4*)(mrow + 4*(CB));                         \
          ADDW(m4_.x, 4*(CB)+0, Q0.x, Q1.x, Q2.x, Q3.x)                       \
          ADDW(m4_.y, 4*(CB)+1, Q0.y, Q1.y, Q2.y, Q3.y)                       \
          ADDW(m4_.z, 4*(CB)+2, Q0.z, Q1.z, Q2.z, Q3.z)                       \
          ADDW(m4_.w, 4*(CB)+3, Q0.w, Q1.w, Q2.w, Q3.w) }

#define PROC4Q(P, CB)                                                         \
        PROCC((CB)+0, P##a0, P##a1, P##a2, P##a3)                             \
        PROCC((CB)+1, P##b0, P##b1, P##b2, P##b3)                             \
        PROCC((CB)+2, P##c0, P##c1, P##c2, P##c3)                             \
        PROCC((CB)+3, P##d0, P##d1, P##d2, P##d3)

#define PROC3Q(P, CB)                                                         \
        PROCC((CB)+0, P##a0, P##a1, P##a2, P##a3)                             \
        PROCC((CB)+1, P##b0, P##b1, P##b2, P##b3)                             \
        PROCC((CB)+2, P##c0, P##c1, P##c2, P##c3)

        // prologue: block 0 + the word-156 dwords (consumed at chunk end)
        LOAD4Q(A, 0)
        uint32_t w6_0 = ((const uint32_t*)s0)[156];
        uint32_t w6_1 = ((const uint32_t*)s1)[156];
        uint32_t w6_2 = ((const uint32_t*)s2)[156];
        uint32_t w6_3 = ((const uint32_t*)s3)[156];

        LOAD4Q(B,  4)  PROC4Q(A,  0)      // c 0..3   (words 0..15)
        LOAD4Q(A,  8)  PROC4Q(B,  4)      // c 4..7
        LOAD4Q(B, 12)  PROC4Q(A,  8)      // c 8..11
        LOAD4Q(A, 16)  PROC4Q(B, 12)      // c 12..15
        LOAD4Q(B, 20)  PROC4Q(A, 16)      // c 16..19
        LOAD4Q(A, 24)  PROC4Q(B, 20)      // c 20..23
        LOAD4Q(B, 28)  PROC4Q(A, 24)      // c 24..27
        LOAD4Q(A, 32)  PROC4Q(B, 28)      // c 28..31 (E/I boundary, static)
        LOAD3Q(B, 36)  PROC4Q(A, 32)      // c 32..35
        PROC3Q(B, 36)                     // c 36..38 (words 144..155, inh)
        {   // word 156 (inhibitory)
            uint32_t mL = s_mask156[tx];
            cI0 += __popc(mL & w6_0);
            cI1 += __popc(mL & w6_1);
            cI2 += __popc(mL & w6_2);
            cI3 += __popc(mL & w6_3);
        }
#undef PROC3Q
#undef PROC4Q
#undef PROCC
#undef ADDW
#undef LOAD3Q
#undef LOAD4Q

        // ---- 4 sequential neuron updates + write-once ring publish ----
#define BRUNEL_STEP(kk, xk)                                                   \
        {                                                                     \
            const int t = t0 + kk;                                            \
            float cur = 0.1f * (float)cE##kk - 0.5f * (float)cI##kk;          \
            v = v * 0.95f + (cur + xk);                                       \
            bool s = act && (v >= 1.0f);                                      \
            float sflag = s ? 1.0f : 0.0f;                                    \
            float vout  = s ? 0.0f : v;                                       \
            if (act) {                                                        \
                size_t o = ((size_t)t * NB + b) * NN + i;                     \
                out_spk[o] = sflag;                                           \
                out_vs[o]  = vout;                                            \
            }                                                                 \
            v = vout;                                                         \
            unsigned long long bm = __ballot(s);                              \
            if ((lane & 31) == 0 && act && t <= TSTEPS - 1 - NDELAY) {        \
                uint32_t wd = (lane == 0) ? (uint32_t)bm : (uint32_t)(bm >> 32); \
                __hip_atomic_store(                                           \
                    &ring[((size_t)(t + NDELAY) * NB + b) * RW + (i >> 5)],   \
                    wd, __ATOMIC_RELAXED, __HIP_MEMORY_SCOPE_AGENT);          \
            }                                                                 \
        }
        BRUNEL_STEP(0, x0)
        BRUNEL_STEP(1, x1)
        BRUNEL_STEP(2, x2)
        BRUNEL_STEP(3, x3)
#undef BRUNEL_STEP

        // ---- arrive: per-wave store drain, block barrier, relaxed add ----
        asm volatile("s_waitcnt vmcnt(0)" ::: "memory");  // ring stores at LLC
        __syncthreads();
        if (tx == 0)
            __hip_atomic_fetch_add(barc + (size_t)m * BARSTRIDE, 1,
                                   __ATOMIC_RELAXED, __HIP_MEMORY_SCOPE_AGENT);
    }
}

// ---------------------------------------------------------------------------
extern "C" void kernel_launch(void* const* d_in, const int* in_sizes, int n_in,
                              void* d_out, int out_size, void* d_ws, size_t ws_size,
                              hipStream_t stream)
{
    const float* ext = (const float*)d_in[0];   // [T,B,N] fp32
    const float* W   = (const float*)d_in[1];   // [N,N]   fp32

    float* out_spk = (float*)d_out;                          // [T,B,N]
    float* out_vs  = out_spk + (size_t)TSTEPS * NB * NN;     // [T,B,N]

    uint8_t*  ws   = (uint8_t*)d_ws;
    uint32_t* mask = (uint32_t*)(ws);
    int*      barc = (int*)(ws + BAR_OFF);
    uint32_t* ring = (uint32_t*)(ws + RING_OFF);

    // zero mask (pad cols) + per-chunk counters + whole write-once ring
    // (slots 0..14 MUST be zero: they serve ts<0 reads)
    hipMemsetAsync(ws, 0, ZERO_BYTES, stream);

    dim3 gmask(NIPAD / IPB, NN);   // (20, 5000)
    _Brunel_build_mask<<<gmask, IPB, 0, stream>>>(W, mask);

    _Brunel_persist<<<NBLK, IPB, 0, stream>>>(ext, mask, ring, barc,
                                              out_spk, out_vs);
}